// Round 15
// baseline (176.230 us; speedup 1.0000x reference)
//
#include <hip/hip_runtime.h>
#include <hip/hip_cooperative_groups.h>
#include <stdint.h>

namespace cg = cooperative_groups;

// Problem constants (match reference)
#define NFEAT 3072          // C*H*W
#define NWORD 2             // 128 batch bits / 64
#define NK 64
#define NP 784
#define NG 8
#define KP (NK * NP)        // 50176 = 256 * 196 exactly
#define NL1 64000
#define NL2 32000
#define NCLS 10
#define NB 128
#define JBLK 128            // j's per lin2 chunk; 3200 % 128 == 0
#define GRID 256            // 1 block per CU, co-resident (48 KB LDS < 160 KB)
#define BLK 256
#define ITEMS_PER_BLK (KP / GRID)   // 196

// Truth-table gate. op bit0 -> (a=1,b=1), bit1 -> (a=1,b=0), bit2 -> (a=0,b=1),
// bit3 -> (a=0,b=0). Verified against ALL 16 COEF rows (op IS the truth table).
// Mux form: r = sel(A, sel(B,m3,m2), sel(B,m1,m0)), sel -> v_bfi_b32.
__device__ __forceinline__ uint64_t bsel64(uint64_t x, uint64_t p, uint64_t q) {
    return (x & p) | (~x & q);
}
__device__ __forceinline__ ulonglong2 gate128(ulonglong2 A, ulonglong2 B, int op) {
    uint64_t m3 = (uint64_t)0 - (uint64_t)((op >> 0) & 1);
    uint64_t m2 = (uint64_t)0 - (uint64_t)((op >> 1) & 1);
    uint64_t m1 = (uint64_t)0 - (uint64_t)((op >> 2) & 1);
    uint64_t m0 = (uint64_t)0 - (uint64_t)((op >> 3) & 1);
    ulonglong2 r;
    r.x = bsel64(A.x, bsel64(B.x, m3, m2), bsel64(B.x, m1, m0));
    r.y = bsel64(A.y, bsel64(B.y, m3, m2), bsel64(B.y, m1, m0));
    return r;
}

// Single cooperative kernel: pack -> grid.sync -> conv -> grid.sync -> lin1+lin2+sum.
// Removes 2 graph-node gaps + 2 launch tails from the serial chain.
__global__ __launch_bounds__(BLK) void fused_all(
    const float* __restrict__ x,
    const int* __restrict__ cl, const int* __restrict__ cr,
    const int* __restrict__ o0, const int* __restrict__ o1,
    const int* __restrict__ o2, const int* __restrict__ o3,
    const int* __restrict__ a1, const int* __restrict__ b1,
    const int* __restrict__ p1,
    const int* __restrict__ a2, const int* __restrict__ b2,
    const int* __restrict__ p2,
    uint64_t* __restrict__ xb, uint64_t* __restrict__ z,
    float* __restrict__ out) {
    __shared__ alignas(16) uint64_t sxb[NFEAT * NWORD];   // 48 KB, reused per phase
    cg::grid_group grid = cg::this_grid();

    // ---- Phase A: ballot bit-pack (lane <-> batch row) + zero d_out ----
    {
        int gt = blockIdx.x * BLK + threadIdx.x;
        if (gt < NB * NCLS) out[gt] = 0.0f;
        int wave = gt >> 6;            // 0..1023
        int lane = gt & 63;
#pragma unroll
        for (int it = 0; it < (NFEAT * NWORD) / 1024; ++it) {   // 6 tasks/wave
            int task = wave + it * 1024;                        // 0..6143
            int f = task >> 1, w = task & 1;
            float val = x[(size_t)(w * 64 + lane) * NFEAT + f];
            uint64_t m = __ballot(val != 0.0f);
            if (lane == 0) xb[f * NWORD + w] = m;
        }
    }
    grid.sync();

    // ---- Phase B: conv tree over 196 items/block, ALL 256 CUs busy;
    //      staging stays 12 iters x 256 threads (r11 lesson: don't double it) ----
    {
        ulonglong2* s2 = reinterpret_cast<ulonglong2*>(sxb);
        const ulonglong2* g2 = reinterpret_cast<const ulonglong2*>(xb);
        for (int i = threadIdx.x; i < NFEAT; i += BLK)
            s2[i] = g2[i];
        __syncthreads();

        if (threadIdx.x < ITEMS_PER_BLK) {
            int t = blockIdx.x * ITEMS_PER_BLK + threadIdx.x;   // coalesced
            int k = t / NP;
            const int4* cl4 = reinterpret_cast<const int4*>(cl + (size_t)t * NG);
            const int4* cr4 = reinterpret_cast<const int4*>(cr + (size_t)t * NG);
            int4 l0 = cl4[0], l1 = cl4[1];
            int4 r0 = cr4[0], r1 = cr4[1];
            int la[NG] = {l0.x, l0.y, l0.z, l0.w, l1.x, l1.y, l1.z, l1.w};
            int rb[NG] = {r0.x, r0.y, r0.z, r0.w, r1.x, r1.y, r1.z, r1.w};
            int op0[NG], op1[4], op2[2], op3;
#pragma unroll
            for (int g = 0; g < NG; ++g) op0[g] = o0[k * NG + g];
#pragma unroll
            for (int g = 0; g < 4; ++g) op1[g] = o1[k * 4 + g];
#pragma unroll
            for (int g = 0; g < 2; ++g) op2[g] = o2[k * 2 + g];
            op3 = o3[k];

            const ulonglong2* sxb2 = reinterpret_cast<const ulonglong2*>(sxb);
            ulonglong2 gg[NG];
#pragma unroll
            for (int g = 0; g < NG; ++g)
                gg[g] = gate128(sxb2[la[g]], sxb2[rb[g]], op0[g]);
#pragma unroll
            for (int g = 0; g < 4; ++g)
                gg[g] = gate128(gg[2 * g], gg[2 * g + 1], op1[g]);
#pragma unroll
            for (int g = 0; g < 2; ++g)
                gg[g] = gate128(gg[2 * g], gg[2 * g + 1], op2[g]);
            reinterpret_cast<ulonglong2*>(z)[t] = gate128(gg[0], gg[1], op3);
        }
    }
    grid.sync();

    // ---- Phase C: fused lin1+lin2+GroupSum (blocks 0..249, one 128-j chunk) ----
    // 256 threads: each computes ONE z1 value (thread pair 2u,2u+1 -> j=u's
    // za/zb) -> 2x more independent 3-level gather chains than 128-thread
    // version. LDS reuse of sxb: zs[256] ulonglong2 (4 KB) then s[2][128] (2 KB).
    if (blockIdx.x < (NL2 / JBLK)) {
        ulonglong2* zs = reinterpret_cast<ulonglong2*>(sxb);        // [0,4096) B
        uint64_t* sbuf = sxb + 512;                                 // [4096,6144) B
        const int chunks_per_cls = (NL2 / NCLS) / JBLK;             // 25
        int c = blockIdx.x / chunks_per_cls;
        int jbase = c * (NL2 / NCLS) + (blockIdx.x % chunks_per_cls) * JBLK;

        int u = threadIdx.x >> 1, role = threadIdx.x & 1;
        int j = jbase + u;
        int idx = role ? b2[j] : a2[j];
        const ulonglong2* z2p = reinterpret_cast<const ulonglong2*>(z);
        zs[threadIdx.x] = gate128(z2p[a1[idx]], z2p[b1[idx]], p1[idx]);
        __syncthreads();

        if (threadIdx.x < JBLK) {
            ulonglong2 r = gate128(zs[2 * threadIdx.x], zs[2 * threadIdx.x + 1],
                                   p2[jbase + threadIdx.x]);
            sbuf[threadIdx.x] = r.x;               // s[0][j]
            sbuf[JBLK + threadIdx.x] = r.y;        // s[1][j]
        }
        __syncthreads();

        int bb = threadIdx.x & 127;        // batch index
        int half = threadIdx.x >> 7;       // which 64-j half
        int w = bb >> 6, sh = bb & 63;
        const ulonglong2* sp = reinterpret_cast<const ulonglong2*>(sbuf + w * JBLK)
                               + half * (JBLK / 4);
        int cnt = 0;
#pragma unroll
        for (int jj = 0; jj < JBLK / 4; ++jj) {
            ulonglong2 v = sp[jj];         // wave-broadcast reads
            cnt += (int)((v.x >> sh) & 1) + (int)((v.y >> sh) & 1);
        }
        atomicAdd(&out[bb * NCLS + c], (float)cnt);
    }
}

extern "C" void kernel_launch(void* const* d_in, const int* in_sizes, int n_in,
                              void* d_out, int out_size, void* d_ws, size_t ws_size,
                              hipStream_t stream) {
    const float* x  = (const float*)d_in[0];
    const int* cl   = (const int*)d_in[1];
    const int* cr   = (const int*)d_in[2];
    const int* o0   = (const int*)d_in[3];
    const int* o1   = (const int*)d_in[4];
    const int* o2   = (const int*)d_in[5];
    const int* o3   = (const int*)d_in[6];
    const int* a1   = (const int*)d_in[7];
    const int* b1   = (const int*)d_in[8];
    const int* p1   = (const int*)d_in[9];
    const int* a2   = (const int*)d_in[10];
    const int* b2   = (const int*)d_in[11];
    const int* p2   = (const int*)d_in[12];
    float* out = (float*)d_out;

    uint8_t* ws = (uint8_t*)d_ws;
    uint64_t* xb = (uint64_t*)(ws);                                   // 48 KB
    uint64_t* z  = (uint64_t*)(ws + 64 * 1024);                       // 784 KB

    void* args[] = {(void*)&x,  (void*)&cl, (void*)&cr, (void*)&o0, (void*)&o1,
                    (void*)&o2, (void*)&o3, (void*)&a1, (void*)&b1, (void*)&p1,
                    (void*)&a2, (void*)&b2, (void*)&p2, (void*)&xb, (void*)&z,
                    (void*)&out};
    hipLaunchCooperativeKernel(fused_all, dim3(GRID), dim3(BLK), args, 0, stream);
}

// Round 16
// 102.976 us; speedup vs baseline: 1.7114x; 1.7114x over previous
//
#include <hip/hip_runtime.h>
#include <stdint.h>

// Problem constants (match reference)
#define NFEAT 3072          // C*H*W
#define NWORD 2             // 128 batch bits / 64
#define NK 64
#define NP 784
#define NG 8
#define KP (NK * NP)        // 50176
#define NL1 64000
#define NL2 32000
#define NCLS 10
#define NB 128
#define JBLK 128            // j's per lin2 chunk; 3200 % 128 == 0

// Truth-table gate. op bit0 -> (a=1,b=1), bit1 -> (a=1,b=0), bit2 -> (a=0,b=1),
// bit3 -> (a=0,b=0). Verified against ALL 16 COEF rows (op IS the truth table).
// Mux form: r = sel(A, sel(B,m3,m2), sel(B,m1,m0)), sel -> v_bfi_b32.
__device__ __forceinline__ uint64_t bsel64(uint64_t x, uint64_t p, uint64_t q) {
    return (x & p) | (~x & q);
}
__device__ __forceinline__ ulonglong2 gate128(ulonglong2 A, ulonglong2 B, int op) {
    uint64_t m3 = (uint64_t)0 - (uint64_t)((op >> 0) & 1);
    uint64_t m2 = (uint64_t)0 - (uint64_t)((op >> 1) & 1);
    uint64_t m1 = (uint64_t)0 - (uint64_t)((op >> 2) & 1);
    uint64_t m0 = (uint64_t)0 - (uint64_t)((op >> 3) & 1);
    ulonglong2 r;
    r.x = bsel64(A.x, bsel64(B.x, m3, m2), bsel64(B.x, m1, m0));
    r.y = bsel64(A.y, bsel64(B.y, m3, m2), bsel64(B.y, m1, m0));
    return r;
}

// ---- 1. Bit-pack via wave ballot: lane <-> batch row, so __ballot(x != 0)
//      IS the packed 64-bit word. One wave per (feature, word); 1536 blocks.
//      Also zeroes d_out (harness re-poisons it to 0xAA before every call). ----
__global__ __launch_bounds__(256) void pack_kernel(const float* __restrict__ x,
                                                   uint64_t* __restrict__ xb,
                                                   float* __restrict__ out) {
    int gt = blockIdx.x * 256 + threadIdx.x;
    if (gt < NB * NCLS) out[gt] = 0.0f;          // fused output zeroing
    int fw = gt >> 6;                            // wave id 0..6143
    int lane = gt & 63;
    int f = fw >> 1, w = fw & 1;
    float val = x[(size_t)(w * 64 + lane) * NFEAT + f];
    uint64_t m = __ballot(val != 0.0f);          // bit i = lane i = batch w*64+i
    if (lane == 0) xb[f * NWORD + w] = m;
}

// ---- 2. Conv logic layer + 3-level tree reduce -> z[KP][NWORD] ----
// One thread per (k,p), both batch words (ILP-2 in .x/.y): 196 blocks x 256.
// (392x128 regressed: doubled per-consumer staging. grid.sync fusion
// regressed 79 us: ~30 us per sync on gfx950. Keep separate kernels.)
__global__ __launch_bounds__(256) void conv_kernel(
    const uint64_t* __restrict__ xb,
    const int* __restrict__ cl, const int* __restrict__ cr,
    const int* __restrict__ o0, const int* __restrict__ o1,
    const int* __restrict__ o2, const int* __restrict__ o3,
    uint64_t* __restrict__ z) {
    __shared__ uint64_t sxb[NFEAT * NWORD];   // 48 KB bit table
    {   // 16B staging: 3072 ulonglong2 entries / 256 threads = 12 iterations
        ulonglong2* s2 = reinterpret_cast<ulonglong2*>(sxb);
        const ulonglong2* g2 = reinterpret_cast<const ulonglong2*>(xb);
        for (int i = threadIdx.x; i < NFEAT; i += blockDim.x)
            s2[i] = g2[i];
    }
    __syncthreads();

    int t = blockIdx.x * 256 + threadIdx.x;
    if (t >= KP) return;
    int k = t / NP;

    // 8 left + 8 right indices as four int4 loads (32B contiguous per thread)
    const int4* cl4 = reinterpret_cast<const int4*>(cl + (size_t)t * NG);
    const int4* cr4 = reinterpret_cast<const int4*>(cr + (size_t)t * NG);
    int4 l0 = cl4[0], l1 = cl4[1];
    int4 r0 = cr4[0], r1 = cr4[1];
    int la[NG] = {l0.x, l0.y, l0.z, l0.w, l1.x, l1.y, l1.z, l1.w};
    int rb[NG] = {r0.x, r0.y, r0.z, r0.w, r1.x, r1.y, r1.z, r1.w};

    // Hoist all op indices (L1-hot, wave-uniform per k)
    int op0[NG], op1[4], op2[2], op3;
#pragma unroll
    for (int g = 0; g < NG; ++g) op0[g] = o0[k * NG + g];
#pragma unroll
    for (int g = 0; g < 4; ++g) op1[g] = o1[k * 4 + g];
#pragma unroll
    for (int g = 0; g < 2; ++g) op2[g] = o2[k * 2 + g];
    op3 = o3[k];

    const ulonglong2* sxb2 = reinterpret_cast<const ulonglong2*>(sxb);
    ulonglong2 gg[NG];
#pragma unroll
    for (int g = 0; g < NG; ++g) {
        ulonglong2 va = sxb2[la[g]];           // one ds_read_b128 per operand
        ulonglong2 vb = sxb2[rb[g]];
        gg[g] = gate128(va, vb, op0[g]);
    }
#pragma unroll
    for (int g = 0; g < 4; ++g)
        gg[g] = gate128(gg[2 * g], gg[2 * g + 1], op1[g]);
#pragma unroll
    for (int g = 0; g < 2; ++g)
        gg[g] = gate128(gg[2 * g], gg[2 * g + 1], op2[g]);
    reinterpret_cast<ulonglong2*>(z)[t] = gate128(gg[0], gg[1], op3);
}

// ---- 3. Fused lin1+lin2+GroupSum, 256 threads/block.
// lin2 makes NL2*2 = 64000 references into the 64000-entry z1 table (1.0 avg
// use) -> recompute z1 on the fly, no z1 round-trip. NEW vs r10: each thread
// computes ONE z1 chain (two threads per j: role 0 -> za, role 1 -> zb), so a
// block exposes 256 independent 3-deep L2-gather chains instead of 128 pairs
// of serial chains -> 2x latency-hiding in the worst kernel (was 2 waves/CU).
__global__ __launch_bounds__(256) void lin2_fused_kernel(
    const uint64_t* __restrict__ z,
    const int* __restrict__ a1, const int* __restrict__ b1,
    const int* __restrict__ p1,
    const int* __restrict__ a2, const int* __restrict__ b2,
    const int* __restrict__ p2, float* __restrict__ out) {
    __shared__ alignas(16) ulonglong2 zs[256];          // z1 values, 4 KB
    __shared__ alignas(16) uint64_t sbuf[NWORD * JBLK]; // z2 bits, 2 KB
    int blk = blockIdx.x;
    const int chunks_per_cls = (NL2 / NCLS) / JBLK;     // 25
    int c = blk / chunks_per_cls;
    int jbase = c * (NL2 / NCLS) + (blk % chunks_per_cls) * JBLK;

    int u = threadIdx.x >> 1, role = threadIdx.x & 1;
    int j = jbase + u;
    int idx = role ? b2[j] : a2[j];
    const ulonglong2* z2p = reinterpret_cast<const ulonglong2*>(z);
    zs[threadIdx.x] = gate128(z2p[a1[idx]], z2p[b1[idx]], p1[idx]);
    __syncthreads();

    if (threadIdx.x < JBLK) {
        ulonglong2 r = gate128(zs[2 * threadIdx.x], zs[2 * threadIdx.x + 1],
                               p2[jbase + threadIdx.x]);
        sbuf[threadIdx.x] = r.x;               // word 0 of z2[j]
        sbuf[JBLK + threadIdx.x] = r.y;        // word 1
    }
    __syncthreads();

    int bb = threadIdx.x & 127;        // batch index 0..127
    int half = threadIdx.x >> 7;       // which 64-j half
    int w = bb >> 6, sh = bb & 63;
    const ulonglong2* sp = reinterpret_cast<const ulonglong2*>(sbuf + w * JBLK)
                           + half * (JBLK / 4);
    int cnt = 0;
#pragma unroll
    for (int jj = 0; jj < JBLK / 4; ++jj) {
        ulonglong2 v = sp[jj];         // wave-broadcast reads
        cnt += (int)((v.x >> sh) & 1) + (int)((v.y >> sh) & 1);
    }
    atomicAdd(&out[bb * NCLS + c], (float)cnt);   // exact small-int adds
}

extern "C" void kernel_launch(void* const* d_in, const int* in_sizes, int n_in,
                              void* d_out, int out_size, void* d_ws, size_t ws_size,
                              hipStream_t stream) {
    const float* x  = (const float*)d_in[0];
    const int* cl   = (const int*)d_in[1];
    const int* cr   = (const int*)d_in[2];
    const int* o0   = (const int*)d_in[3];
    const int* o1   = (const int*)d_in[4];
    const int* o2   = (const int*)d_in[5];
    const int* o3   = (const int*)d_in[6];
    const int* a1   = (const int*)d_in[7];
    const int* b1   = (const int*)d_in[8];
    const int* p1   = (const int*)d_in[9];
    const int* a2   = (const int*)d_in[10];
    const int* b2   = (const int*)d_in[11];
    const int* p2   = (const int*)d_in[12];
    float* out = (float*)d_out;

    uint8_t* ws = (uint8_t*)d_ws;
    uint64_t* xb = (uint64_t*)(ws);                                   // 48 KB
    uint64_t* z  = (uint64_t*)(ws + 64 * 1024);                       // 784 KB

    // pack: 6144 waves = 1536 blocks (exactly NFEAT*NWORD waves, no tail)
    pack_kernel<<<(NFEAT * NWORD * 64) / 256, 256, 0, stream>>>(x, xb, out);
    // conv: 50176 threads -> 196 blocks x 256
    conv_kernel<<<(KP + 255) / 256, 256, 0, stream>>>(xb, cl, cr, o0, o1, o2, o3, z);
    // lin1+lin2+sum: 250 blocks x 256 threads
    lin2_fused_kernel<<<NL2 / JBLK, 256, 0, stream>>>(z, a1, b1, p1, a2, b2, p2, out);
}

// Round 17
// 96.326 us; speedup vs baseline: 1.8295x; 1.0690x over previous
//
#include <hip/hip_runtime.h>
#include <stdint.h>

// Problem constants (match reference)
#define NFEAT 3072          // C*H*W
#define NWORD 2             // 128 batch bits / 64
#define NK 64               // kernels
#define NP 784              // output positions
#define NG 8                // level-0 gates per (k,p)
#define KP (NK * NP)        // 50176
#define NL1 64000
#define NL2 32000
#define NCLS 10
#define NB 128              // batch
#define JBLK 128            // j's per lin2 block; 3200 % 128 == 0

// Truth-table gate. op bit0 -> (a=1,b=1), bit1 -> (a=1,b=0), bit2 -> (a=0,b=1),
// bit3 -> (a=0,b=0). Verified against ALL 16 COEF rows: the op index's binary
// representation IS the truth table (op1=AND=0001, op6=XOR=0110, op8=NOR=1000,
// op11=(a|~b)=1011, op15=ONE=1111).
// Mux form: r = sel(A, sel(B,m3,m2), sel(B,m1,m0)), sel -> v_bfi_b32.
__device__ __forceinline__ uint64_t bsel64(uint64_t x, uint64_t p, uint64_t q) {
    return (x & p) | (~x & q);
}
__device__ __forceinline__ ulonglong2 gate128(ulonglong2 A, ulonglong2 B, int op) {
    uint64_t m3 = (uint64_t)0 - (uint64_t)((op >> 0) & 1);
    uint64_t m2 = (uint64_t)0 - (uint64_t)((op >> 1) & 1);
    uint64_t m1 = (uint64_t)0 - (uint64_t)((op >> 2) & 1);
    uint64_t m0 = (uint64_t)0 - (uint64_t)((op >> 3) & 1);
    ulonglong2 r;
    r.x = bsel64(A.x, bsel64(B.x, m3, m2), bsel64(B.x, m1, m0));
    r.y = bsel64(A.y, bsel64(B.y, m3, m2), bsel64(B.y, m1, m0));
    return r;
}

// ---- 1. Bit-pack via wave ballot: lane <-> batch row, so __ballot(x != 0)
//      IS the packed 64-bit word. One wave per (feature, word); 1536 blocks.
//      Also zeroes d_out (harness re-poisons it to 0xAA before every call). ----
__global__ __launch_bounds__(256) void pack_kernel(const float* __restrict__ x,
                                                   uint64_t* __restrict__ xb,
                                                   float* __restrict__ out) {
    int gt = blockIdx.x * 256 + threadIdx.x;
    if (gt < NB * NCLS) out[gt] = 0.0f;          // fused output zeroing
    int fw = gt >> 6;                            // wave id 0..6143
    int lane = gt & 63;
    int f = fw >> 1, w = fw & 1;
    float val = x[(size_t)(w * 64 + lane) * NFEAT + f];
    uint64_t m = __ballot(val != 0.0f);          // bit i = lane i = batch w*64+i
    if (lane == 0) xb[f * NWORD + w] = m;
}

// ---- 2. Conv logic layer + 3-level tree reduce -> z[KP][NWORD] ----
// One thread per (k,p), both batch words (ILP-2 in .x/.y): 196 blocks x 256.
// (392x128 regressed: doubled per-consumer staging. grid.sync fusion
// regressed 79 us: ~30 us per sync on gfx950. lin2 256-thread restructure
// regressed ~3 us: extra barrier + LDS round-trip. This is the measured-best
// configuration: 97.2 us.)
__global__ __launch_bounds__(256) void conv_kernel(
    const uint64_t* __restrict__ xb,
    const int* __restrict__ cl, const int* __restrict__ cr,
    const int* __restrict__ o0, const int* __restrict__ o1,
    const int* __restrict__ o2, const int* __restrict__ o3,
    uint64_t* __restrict__ z) {
    __shared__ uint64_t sxb[NFEAT * NWORD];   // 48 KB bit table
    {   // 16B staging: 3072 ulonglong2 entries / 256 threads = 12 iterations
        ulonglong2* s2 = reinterpret_cast<ulonglong2*>(sxb);
        const ulonglong2* g2 = reinterpret_cast<const ulonglong2*>(xb);
        for (int i = threadIdx.x; i < NFEAT; i += blockDim.x)
            s2[i] = g2[i];
    }
    __syncthreads();

    int t = blockIdx.x * 256 + threadIdx.x;
    if (t >= KP) return;
    int k = t / NP;

    // 8 left + 8 right indices as four int4 loads (32B contiguous per thread)
    const int4* cl4 = reinterpret_cast<const int4*>(cl + (size_t)t * NG);
    const int4* cr4 = reinterpret_cast<const int4*>(cr + (size_t)t * NG);
    int4 l0 = cl4[0], l1 = cl4[1];
    int4 r0 = cr4[0], r1 = cr4[1];
    int la[NG] = {l0.x, l0.y, l0.z, l0.w, l1.x, l1.y, l1.z, l1.w};
    int rb[NG] = {r0.x, r0.y, r0.z, r0.w, r1.x, r1.y, r1.z, r1.w};

    // Hoist all op indices (L1-hot, wave-uniform per k)
    int op0[NG], op1[4], op2[2], op3;
#pragma unroll
    for (int g = 0; g < NG; ++g) op0[g] = o0[k * NG + g];
#pragma unroll
    for (int g = 0; g < 4; ++g) op1[g] = o1[k * 4 + g];
#pragma unroll
    for (int g = 0; g < 2; ++g) op2[g] = o2[k * 2 + g];
    op3 = o3[k];

    const ulonglong2* sxb2 = reinterpret_cast<const ulonglong2*>(sxb);
    ulonglong2 gg[NG];
#pragma unroll
    for (int g = 0; g < NG; ++g) {
        ulonglong2 va = sxb2[la[g]];           // one ds_read_b128 per operand
        ulonglong2 vb = sxb2[rb[g]];
        gg[g] = gate128(va, vb, op0[g]);
    }
#pragma unroll
    for (int g = 0; g < 4; ++g)
        gg[g] = gate128(gg[2 * g], gg[2 * g + 1], op1[g]);
#pragma unroll
    for (int g = 0; g < 2; ++g)
        gg[g] = gate128(gg[2 * g], gg[2 * g + 1], op2[g]);
    reinterpret_cast<ulonglong2*>(z)[t] = gate128(gg[0], gg[1], op3);
}

// ---- 3. Fused lin1+lin2+GroupSum.
// lin2 makes NL2*2 = 64000 references into the NL1 = 64000-entry z1 table —
// exactly 1.0 average use per element, so recomputing z1 on the fly costs the
// SAME number of gate evals and deletes the 2 MB z1 round-trip + one launch.
// One block per (class, 128-j chunk); one thread per j, both words (ILP-2,
// 16B gathers, one index set per j). Phase 2: thread bb extracts bit bb
// across the 128 j's via 64 broadcast ds_read_b128 and atomically adds into
// out[bb][c]. Counts are small ints -> float atomicAdd exact, order-free.
__global__ __launch_bounds__(JBLK) void lin2_fused_kernel(
    const uint64_t* __restrict__ z,
    const int* __restrict__ a1, const int* __restrict__ b1,
    const int* __restrict__ p1,
    const int* __restrict__ a2, const int* __restrict__ b2,
    const int* __restrict__ p2, float* __restrict__ out) {
    __shared__ alignas(16) uint64_t s[NWORD][JBLK];
    int blk = blockIdx.x;
    const int chunks_per_cls = (NL2 / NCLS) / JBLK;   // 25
    int c = blk / chunks_per_cls;
    int j = c * (NL2 / NCLS) + (blk % chunks_per_cls) * JBLK + threadIdx.x;

    int ia = a2[j], ib = b2[j], op = p2[j];
    // z1[ia], z1[ib] recomputed from the conv output table z
    int iaa = a1[ia], iab = b1[ia], opa = p1[ia];
    int iba = a1[ib], ibb = b1[ib], opb = p1[ib];
    const ulonglong2* z2p = reinterpret_cast<const ulonglong2*>(z);
    ulonglong2 za = gate128(z2p[iaa], z2p[iab], opa);
    ulonglong2 zb = gate128(z2p[iba], z2p[ibb], opb);
    ulonglong2 zz = gate128(za, zb, op);
    s[0][threadIdx.x] = zz.x;
    s[1][threadIdx.x] = zz.y;
    __syncthreads();

    int bb = threadIdx.x;          // batch index 0..127
    int w = bb >> 6, sh = bb & 63;
    const ulonglong2* sp = reinterpret_cast<const ulonglong2*>(s[w]);
    int cnt = 0;
#pragma unroll 16
    for (int jj = 0; jj < JBLK / 2; ++jj) {
        ulonglong2 v = sp[jj];     // wave-broadcast (all lanes same address)
        cnt += (int)((v.x >> sh) & 1) + (int)((v.y >> sh) & 1);
    }
    atomicAdd(&out[bb * NCLS + c], (float)cnt);
}

extern "C" void kernel_launch(void* const* d_in, const int* in_sizes, int n_in,
                              void* d_out, int out_size, void* d_ws, size_t ws_size,
                              hipStream_t stream) {
    const float* x  = (const float*)d_in[0];
    const int* cl   = (const int*)d_in[1];
    const int* cr   = (const int*)d_in[2];
    const int* o0   = (const int*)d_in[3];
    const int* o1   = (const int*)d_in[4];
    const int* o2   = (const int*)d_in[5];
    const int* o3   = (const int*)d_in[6];
    const int* a1   = (const int*)d_in[7];
    const int* b1   = (const int*)d_in[8];
    const int* p1   = (const int*)d_in[9];
    const int* a2   = (const int*)d_in[10];
    const int* b2   = (const int*)d_in[11];
    const int* p2   = (const int*)d_in[12];
    float* out = (float*)d_out;

    uint8_t* ws = (uint8_t*)d_ws;
    uint64_t* xb = (uint64_t*)(ws);                                   // 48 KB
    uint64_t* z  = (uint64_t*)(ws + 64 * 1024);                       // 784 KB

    // pack: 6144 waves = 1536 blocks (exactly NFEAT*NWORD waves, no tail)
    pack_kernel<<<(NFEAT * NWORD * 64) / 256, 256, 0, stream>>>(x, xb, out);
    // conv: 50176 threads -> 196 blocks x 256
    conv_kernel<<<(KP + 255) / 256, 256, 0, stream>>>(xb, cl, cr, o0, o1, o2, o3, z);
    // lin1+lin2+sum: 250 blocks x 128 threads
    lin2_fused_kernel<<<NL2 / JBLK, JBLK, 0, stream>>>(z, a1, b1, p1, a2, b2, p2, out);
}